// Round 2
// baseline (301.128 us; speedup 1.0000x reference)
//
#include <hip/hip_runtime.h>
#include <hip/hip_bf16.h>

#define N_NODES 50000
#define N_EDGES 600000
#define DIM 128
#define EPS 1e-5f

#define NPB 64                                   // nodes per gemm tile
#define GEMM_GRID ((N_NODES + NPB - 1) / NPB)    // 782
#define GEMM_THREADS 512                         // 8 waves = 8 ch-slices
#define HIST_BLOCKS 512
#define NSLICE 8                                 // channel slices -> XCDs
#define GPB 256                                  // gather blocks per slice
#define SCAN_NB 49                               // ceil(50000/1024)

// GEMM: lane = node (x via conflict-free transposed LDS, ds_read_b32 = 64 unique
// floats/inst), wave = 16-channel slice. W row-chunk addresses are wave-uniform
// (readfirstlane base) -> compiler promotes to scalar (SMEM) loads; FMA operand
// comes through the SGPR slot. 16 FMAs per LDS read.
__device__ __forceinline__ void gemm_body(
    const float* __restrict__ xin, const float* __restrict__ W,
    const float* __restrict__ bias, const float* __restrict__ tptr,
    float4* __restrict__ s_sliced, int tile, float* xsT)
{
    const int tid = threadIdx.x;
    const int nb = tile * NPB;
    const float4* xin4 = (const float4*)xin;

    // stage x tile transposed: element k of node nl lands at
    // xsT[k*64 + (nl ^ ((k>>2)&31))] — writes and reads both hit each bank with
    // exactly 2 lanes per instruction (free).
#pragma unroll
    for (int i = 0; i < 4; ++i) {
        int f4 = tid + i * GEMM_THREADS;         // 0..2047
        int nl = f4 >> 5;                        // local node 0..63
        int q  = f4 & 31;                        // float4 index along k
        int node = nb + nl;
        float4 v = make_float4(0.f, 0.f, 0.f, 0.f);
        if (node < N_NODES) v = xin4[(size_t)node * 32 + q];
        int k0  = q * 4;
        int col = nl ^ q;                        // (k>>2)&31 == q for all 4 rows
        xsT[((k0 + 0) << 6) + col] = v.x;
        xsT[((k0 + 1) << 6) + col] = v.y;
        xsT[((k0 + 2) << 6) + col] = v.z;
        xsT[((k0 + 3) << 6) + col] = v.w;
    }
    __syncthreads();

    const int lane = tid & 63;                   // = node within tile
    const int wv_  = tid >> 6;                   // 0..7 = output slice
    const int cbase = __builtin_amdgcn_readfirstlane(wv_ << 4);  // provably uniform
    const float* Wb = W + DIM + cbase;           // x-part row k: Wb + k*DIM

#define XV(k) xsT[((k) << 6) + (lane ^ (((k) >> 2) & 31))]

    float acc[16];
#pragma unroll
    for (int c = 0; c < 16; ++c) acc[c] = 0.f;

#pragma unroll 2
    for (int k = 0; k < DIM; k += 4) {
        // 4 rows x 16 uniform W floats (contiguous 64B per row -> SMEM-friendly)
        float w[4][16];
#pragma unroll
        for (int r = 0; r < 4; ++r) {
            float4 a = *(const float4*)&Wb[(k + r) * DIM + 0];
            float4 b = *(const float4*)&Wb[(k + r) * DIM + 4];
            float4 c = *(const float4*)&Wb[(k + r) * DIM + 8];
            float4 d = *(const float4*)&Wb[(k + r) * DIM + 12];
            w[r][0] = a.x;  w[r][1] = a.y;  w[r][2] = a.z;  w[r][3] = a.w;
            w[r][4] = b.x;  w[r][5] = b.y;  w[r][6] = b.z;  w[r][7] = b.w;
            w[r][8] = c.x;  w[r][9] = c.y;  w[r][10] = c.z; w[r][11] = c.w;
            w[r][12] = d.x; w[r][13] = d.y; w[r][14] = d.z; w[r][15] = d.w;
        }
#pragma unroll
        for (int r = 0; r < 4; ++r) {
            float xv = XV(k + r);
#pragma unroll
            for (int c = 0; c < 16; ++c)
                acc[c] = fmaf(w[r][c], xv, acc[c]);
        }
    }
#undef XV

    const float tval = *tptr;
    const int node = nb + lane;
    if (node < N_NODES) {
        const size_t obase = ((size_t)wv_ * N_NODES + node) * 4;
#pragma unroll
        for (int qq = 0; qq < 4; ++qq) {
            float4 r;
            r.x = acc[qq * 4 + 0] + tval * W[cbase + qq * 4 + 0] + bias[cbase + qq * 4 + 0];
            r.y = acc[qq * 4 + 1] + tval * W[cbase + qq * 4 + 1] + bias[cbase + qq * 4 + 1];
            r.z = acc[qq * 4 + 2] + tval * W[cbase + qq * 4 + 2] + bias[cbase + qq * 4 + 2];
            r.w = acc[qq * 4 + 3] + tval * W[cbase + qq * 4 + 3] + bias[cbase + qq * 4 + 3];
            s_sliced[obase + qq] = r;
        }
    }
}

// gemm layer-1 + histogram (independent work, merged dispatch)
__global__ __launch_bounds__(GEMM_THREADS) void gemm_hist_kernel(
    const float* __restrict__ xin, const float* __restrict__ W,
    const float* __restrict__ bias, const float* __restrict__ tptr,
    float4* __restrict__ s_sliced,
    const int* __restrict__ tgt, int* __restrict__ cursor)
{
    __shared__ float xsT[DIM * 64];              // 32 KB (hist blocks leave it unused)
    if (blockIdx.x < GEMM_GRID) {
        gemm_body(xin, W, bias, tptr, s_sliced, blockIdx.x, xsT);
    } else {
        int e = (blockIdx.x - GEMM_GRID) * GEMM_THREADS + threadIdx.x;
        for (; e < N_EDGES; e += HIST_BLOCKS * GEMM_THREADS)
            atomicAdd(&cursor[tgt[e]], 1);
    }
}

__global__ __launch_bounds__(GEMM_THREADS) void gemm_kernel(
    const float* __restrict__ xin, const float* __restrict__ W,
    const float* __restrict__ bias, const float* __restrict__ tptr,
    float4* __restrict__ s_sliced)
{
    __shared__ float xsT[DIM * 64];
    gemm_body(xin, W, bias, tptr, s_sliced, blockIdx.x, xsT);
}

// merged scan (pass1 + bsum-scan + rowptr write), 49 blocks — all co-resident.
// flags[0]=ticket, flags[1]=bsum2-ready (pre-zeroed by memset)
__global__ __launch_bounds__(256) void scan_kernel(
    const int* __restrict__ counts, int* __restrict__ bsum,
    int* __restrict__ bsum2, int* __restrict__ flags,
    int* __restrict__ rowptr)
{
    __shared__ int sh[256];
    __shared__ int amILast;
    __shared__ int sbase;
    const int tid = threadIdx.x;
    const int b = blockIdx.x;
    const int n4 = N_NODES / 4;                  // 12500

    int idx4 = b * 256 + tid;
    int4 c = make_int4(0, 0, 0, 0);
    if (idx4 < n4) c = ((const int4*)counts)[idx4];
    int tsum = c.x + c.y + c.z + c.w;

    // block-wide inclusive scan
    sh[tid] = tsum;
    __syncthreads();
#pragma unroll
    for (int off = 1; off < 256; off <<= 1) {
        int v = (tid >= off) ? sh[tid - off] : 0;
        __syncthreads();
        sh[tid] += v;
        __syncthreads();
    }
    int incl = sh[tid];

    if (tid == 0) {
        atomicExch(&bsum[b], sh[255]);           // device-scope publish
        amILast = (atomicAdd(&flags[0], 1) == SCAN_NB - 1);
    }
    __syncthreads();

    if (amILast) {
        if (tid < 64) {                          // one wave scans 49 sums
            int v = (tid < SCAN_NB) ? atomicAdd(&bsum[tid], 0) : 0;
            int incl2 = v;
#pragma unroll
            for (int off = 1; off < 64; off <<= 1) {
                int u = __shfl_up(incl2, off);
                if ((threadIdx.x & 63) >= off) incl2 += u;
            }
            if (tid < SCAN_NB) atomicExch(&bsum2[tid], incl2 - v);   // exclusive
        }
        __syncthreads();
        if (tid == 0) atomicExch(&flags[1], 1);
    }

    if (tid == 0) {
        while (atomicAdd(&flags[1], 0) == 0) __builtin_amdgcn_s_sleep(2);
        sbase = atomicAdd(&bsum2[b], 0);
    }
    __syncthreads();

    int base = sbase + incl - tsum;              // exclusive prefix for my int4
    if (idx4 < n4) {
        int4 r;
        r.x = base;
        r.y = base + c.x;
        r.z = r.y + c.y;
        r.w = r.z + c.z;
        ((int4*)rowptr)[idx4] = r;
        if (idx4 == n4 - 1) rowptr[N_NODES] = r.w + c.w;
    }
}

__global__ __launch_bounds__(256) void place_kernel(
    const int* __restrict__ src, const int* __restrict__ tgt,
    const int* __restrict__ rowptr,
    int* __restrict__ cursor, int* __restrict__ eid, int E)
{
    int e = blockIdx.x * 256 + threadIdx.x;
    if (e >= E) return;
    int t = tgt[e];
    int idx = atomicSub(&cursor[t], 1) - 1;
    eid[rowptr[t] + idx] = src[e];
}

// gather + relu + groupnorm (XCD-sliced, node-parallel lanes)
__global__ __launch_bounds__(256) void gather_gn_kernel(
    const float4* __restrict__ s_sliced, const int* __restrict__ rowptr,
    const int* __restrict__ eid,
    const float* __restrict__ gamma, const float* __restrict__ beta,
    float* __restrict__ out, int N)
{
    const int slice = blockIdx.x & 7;
    const int sblk  = blockIdx.x >> 3;
    const int wave  = threadIdx.x >> 6;
    const int lane  = threadIdx.x & 63;
    const int nslot = lane >> 2;
    const int qin   = lane & 3;

    const float4* stab = s_sliced + (size_t)slice * N_NODES * 4;
    const int gch = slice * 16 + qin * 4;
    const float4 gm = *(const float4*)&gamma[gch];
    const float4 bt = *(const float4*)&beta[gch];

    const int wslot0  = sblk * 4 + wave;
    const int nwslots = GPB * 4;

    for (int base = wslot0 * 16; base < N; base += nwslots * 16) {
        int node = base + nslot;
        bool valid = node < N;
        int beg = 0, end = 0;
        if (valid) {
            beg = rowptr[node];
            end = rowptr[node + 1];
        }

        float4 acc = make_float4(0.f, 0.f, 0.f, 0.f);
        int e = beg;
        for (; e + 3 < end; e += 4) {
            int s0 = eid[e];
            int s1 = eid[e + 1];
            int s2 = eid[e + 2];
            int s3 = eid[e + 3];
            float4 v0 = stab[(size_t)s0 * 4 + qin];
            float4 v1 = stab[(size_t)s1 * 4 + qin];
            float4 v2 = stab[(size_t)s2 * 4 + qin];
            float4 v3 = stab[(size_t)s3 * 4 + qin];
            acc.x += (v0.x + v1.x) + (v2.x + v3.x);
            acc.y += (v0.y + v1.y) + (v2.y + v3.y);
            acc.z += (v0.z + v1.z) + (v2.z + v3.z);
            acc.w += (v0.w + v1.w) + (v2.w + v3.w);
        }
        for (; e < end; ++e) {
            int s = eid[e];
            float4 v = stab[(size_t)s * 4 + qin];
            acc.x += v.x;
            acc.y += v.y;
            acc.z += v.z;
            acc.w += v.w;
        }

        if (valid) {
            int deg = end - beg;
            float inv = (deg > 0) ? (1.0f / (float)deg) : 0.0f;
            float ax = fmaxf(acc.x * inv, 0.f);
            float ay = fmaxf(acc.y * inv, 0.f);
            float az = fmaxf(acc.z * inv, 0.f);
            float aw = fmaxf(acc.w * inv, 0.f);
            float mu = 0.25f * (ax + ay + az + aw);
            float dx = ax - mu, dy = ay - mu, dz = az - mu, dw = aw - mu;
            float var = 0.25f * (dx * dx + dy * dy + dz * dz + dw * dw);
            float rs = rsqrtf(var + EPS);
            float4 r;
            r.x = dx * rs * gm.x + bt.x;
            r.y = dy * rs * gm.y + bt.y;
            r.z = dz * rs * gm.z + bt.z;
            r.w = dw * rs * gm.w + bt.w;
            *(float4*)&out[(size_t)node * DIM + gch] = r;
        }
    }
}

extern "C" void kernel_launch(void* const* d_in, const int* in_sizes, int n_in,
                              void* d_out, int out_size, void* d_ws, size_t ws_size,
                              hipStream_t stream) {
    const float* t      = (const float*)d_in[0];
    const float* x      = (const float*)d_in[1];
    const int*   src    = (const int*)d_in[2];
    const int*   tgt    = (const int*)d_in[3];
    const float* W1     = (const float*)d_in[5];
    const float* b1     = (const float*)d_in[6];
    const float* W2     = (const float*)d_in[7];
    const float* b2     = (const float*)d_in[8];
    const float* gamma1 = (const float*)d_in[9];
    const float* beta1  = (const float*)d_in[10];
    const float* gamma2 = (const float*)d_in[11];
    const float* beta2  = (const float*)d_in[12];
    float* out = (float*)d_out;

    const size_t NODE_BYTES = (size_t)N_NODES * DIM * sizeof(float);  // 25.6 MB
    char* ws = (char*)d_ws;
    size_t off = 0;
    float4* s_sliced = (float4*)(ws + off); off += NODE_BYTES;
    int*    rowptr   = (int*)(ws + off);    off += ((size_t)N_NODES + 4) * 4;
    off = (off + 255) & ~(size_t)255;
    int*    cursor   = (int*)(ws + off);    off += ((size_t)N_NODES + 64) * 4;  // counts + flags
    int*    flags    = cursor + N_NODES;    // flags[0..1], pre-zeroed by memset
    off = (off + 255) & ~(size_t)255;
    int*    bsum     = (int*)(ws + off);    off += 64 * 4;
    int*    bsum2    = (int*)(ws + off);    off += 64 * 4;
    off = (off + 255) & ~(size_t)255;
    int*    eid      = (int*)(ws + off);    off += (size_t)N_EDGES * 4;

    const int edge_grid   = (N_EDGES + 255) / 256;     // 2344
    const int gather_grid = NSLICE * GPB;              // 2048

    // 1) zero counts + flags
    hipMemsetAsync(cursor, 0, ((size_t)N_NODES + 64) * 4, stream);
    // 2) gemm layer-1 + histogram (independent, merged)
    gemm_hist_kernel<<<GEMM_GRID + HIST_BLOCKS, GEMM_THREADS, 0, stream>>>(
        x, W1, b1, t, s_sliced, tgt, cursor);
    // 3) scan (pass1 + bsum + rowptr merged; 49 co-resident blocks)
    scan_kernel<<<SCAN_NB, 256, 0, stream>>>(cursor, bsum, bsum2, flags, rowptr);
    // 4) place (full edge-parallel grid)
    place_kernel<<<edge_grid, 256, 0, stream>>>(src, tgt, rowptr, cursor, eid, N_EDGES);
    // 5) gather+GN layer-1  (h lives in d_out)
    gather_gn_kernel<<<gather_grid, 256, 0, stream>>>(s_sliced, rowptr, eid, gamma1, beta1, out, N_NODES);
    // 6) gemm layer-2
    gemm_kernel<<<GEMM_GRID, GEMM_THREADS, 0, stream>>>(out, W2, b2, t, s_sliced);
    // 7) gather+GN layer-2
    gather_gn_kernel<<<gather_grid, 256, 0, stream>>>(s_sliced, rowptr, eid, gamma2, beta2, out, N_NODES);
}